// Round 3
// baseline (227.726 us; speedup 1.0000x reference)
//
#include <hip/hip_runtime.h>
#include <hip/hip_bf16.h>

// SelfAttention: B=4, S=2048, E=1024, fp32 in/out, bf16 internal compute.
// Y[b,j,d] = sum_i softmax_i(Q_j.K_i / sqrt(S)) * V[i,d]
//
// R9: scores/y 8-phase pipeline with INLINE-ASM ds_read_b128 fragment loads.
// Theory: compiler LDS-DMA alias tracking inserts a vmcnt drain before each
// phase's visible lds[] reads, collapsing the counted-vmcnt pipeline to
// 2-phase class (~590 TF, matches m233's 607). Making the ds_reads invisible
// (volatile asm, no memory clobber) removes the inserted drains; ordering is
// provided by s_barrier + counted vmcnt + lgkmcnt(0)+sched_barrier(0)
// (rule #18). qkv/cvt unchanged from R8 (proven ~64/~15 us).

typedef __bf16 bf16x8 __attribute__((ext_vector_type(8)));
typedef float  f32x4  __attribute__((ext_vector_type(4)));

__device__ __forceinline__ unsigned short f2bf(float f) {
    unsigned int u = __float_as_uint(f);
    u = (u + 0x7FFFu + ((u >> 16) & 1u)) >> 16;   // round-to-nearest-even
    return (unsigned short)u;
}

// Converts X + Wq/Wk/Wv fp32->bf16, and zeroes the softmax-denominator array.
__global__ __launch_bounds__(256)
void cvt_all(const float* __restrict__ X,  const float* __restrict__ Wq,
             const float* __restrict__ Wk, const float* __restrict__ Wv,
             unsigned short* __restrict__ Xb,  unsigned short* __restrict__ Wqb,
             unsigned short* __restrict__ Wkb, unsigned short* __restrict__ Wvb,
             float* __restrict__ l) {
    long i = (long)blockIdx.x * 256 + threadIdx.x;   // float4 index
    if (i < 8192) l[i] = 0.0f;                       // 4*2048 row sums
    const float* src; unsigned short* dst; long off;
    if (i < 2097152L) { src = X; dst = Xb; off = i; }
    else {
        long j = i - 2097152L;
        int w = (int)(j >> 18);          // 262144 float4 per 1024^2 matrix
        off = j & 262143L;
        src = (w == 0) ? Wq : (w == 1) ? Wk : Wv;
        dst = (w == 0) ? Wqb : (w == 1) ? Wkb : Wvb;
    }
    float4 v = reinterpret_cast<const float4*>(src)[off];
    ushort4 o;
    o.x = f2bf(v.x); o.y = f2bf(v.y); o.z = f2bf(v.z); o.w = f2bf(v.w);
    reinterpret_cast<ushort4*>(dst)[off] = o;
}

// ======================= R6 m97-style machinery (qkv) =======================
#define GEMM_DECLS                                                      \
    const int t    = threadIdx.x;                                       \
    const int wave = t >> 6;                                            \
    const int lane = t & 63;                                            \
    const int quad = lane >> 4;                                         \
    const int lr   = lane & 15;                                         \
    const int wm   = (wave >> 1) * 64;                                  \
    const int wn   = (wave & 1) * 64;                                   \
    const int sx   = lr & 7;                                            \
    const int lrow = lane >> 3;                                         \
    const int gch  = ((lane & 7) ^ (lrow & 7)) * 8;

#define GEMM_KLOOP(Aptr, Bptr, LDA, LDB)                                \
    for (int k0 = 0; k0 < K; k0 += 64) {                                \
        _Pragma("unroll")                                               \
        for (int r = 0; r < 4; ++r) {                                   \
            const int rowb = wave * 8 + r * 32;                         \
            const int row  = rowb + lrow;                               \
            const long goffA = (long)(m0 + row) * (LDA) + k0 + gch;     \
            const long goffB = (long)(n0 + row) * (LDB) + k0 + gch;     \
            __builtin_amdgcn_global_load_lds(                           \
                (const __attribute__((address_space(1))) void*)((Aptr) + goffA), \
                (__attribute__((address_space(3))) void*)(&lsA[rowb * 64]), 16, 0, 0); \
            __builtin_amdgcn_global_load_lds(                           \
                (const __attribute__((address_space(1))) void*)((Bptr) + goffB), \
                (__attribute__((address_space(3))) void*)(&lsB[rowb * 64]), 16, 0, 0); \
        }                                                               \
        __syncthreads();                                                \
        _Pragma("unroll")                                               \
        for (int h = 0; h < 2; ++h) {                                   \
            const int cp = ((h * 4 + quad) ^ sx) * 8;                   \
            bf16x8 af[4], bfr[4];                                       \
            _Pragma("unroll")                                           \
            for (int i = 0; i < 4; ++i) {                               \
                af[i]  = __builtin_bit_cast(bf16x8,                     \
                          *reinterpret_cast<const uint4*>(&lsA[(wm + i * 16 + lr) * 64 + cp])); \
                bfr[i] = __builtin_bit_cast(bf16x8,                     \
                          *reinterpret_cast<const uint4*>(&lsB[(wn + i * 16 + lr) * 64 + cp])); \
            }                                                           \
            _Pragma("unroll")                                           \
            for (int i = 0; i < 4; ++i)                                 \
                _Pragma("unroll")                                       \
                for (int j = 0; j < 4; ++j)                             \
                    acc[i][j] = __builtin_amdgcn_mfma_f32_16x16x32_bf16(af[i], bfr[j], acc[i][j], 0, 0, 0); \
        }                                                               \
        __syncthreads();                                                \
    }

// Fused QKV projection, XCD-band swizzled 1D grid of 1536 blocks:
// id = g + 8*(x + 8*y_in + 64*z); XCD g owns m-band y = g*8+y_in.
// z=0 -> Q (bf16), z=1 -> K (bf16), z=2 -> V transposed Vt[b][n][s].
__global__ __launch_bounds__(256, 2)
void gemm_qkv(const unsigned short* __restrict__ Xb,
              const unsigned short* __restrict__ Wqb,
              const unsigned short* __restrict__ Wkb,
              const unsigned short* __restrict__ Wvb,
              const float* __restrict__ bq, const float* __restrict__ bk,
              const float* __restrict__ bv_,
              unsigned short* __restrict__ Qb, unsigned short* __restrict__ Kb,
              unsigned short* __restrict__ Vt)
{
    __shared__ unsigned short lsA[128 * 64];
    __shared__ unsigned short lsB[128 * 64];

    const int id  = blockIdx.x;
    const int g   = id & 7;
    const int jj  = id >> 3;
    const int xx  = jj & 7;
    const int yin = (jj >> 3) & 7;
    const int z   = jj >> 6;

    const unsigned short* A = Xb;
    const unsigned short* B = (z == 0) ? Wqb : (z == 1) ? Wkb : Wvb;
    const float* bias       = (z == 0) ? bq  : (z == 1) ? bk  : bv_;

    const int n0 = xx * 128;
    const int m0 = (g * 8 + yin) * 128;
    const int K = 1024;

    GEMM_DECLS
    f32x4 acc[4][4] = {};
    GEMM_KLOOP(A, B, 1024, 1024)

#pragma unroll
    for (int j = 0; j < 4; ++j) {
        const int n = n0 + wn + j * 16 + lr;
        const float bvv = bias[n];
#pragma unroll
        for (int i = 0; i < 4; ++i) {
            const int mbase = m0 + wm + i * 16 + quad * 4;
            if (z < 2) {
                unsigned short* C = (z == 0) ? Qb : Kb;
#pragma unroll
                for (int r = 0; r < 4; ++r)
                    C[(long)(mbase + r) * 1024 + n] = f2bf(acc[i][j][r] + bvv);
            } else {
                ushort4 o;
                o.x = f2bf(acc[i][j][0] + bvv);
                o.y = f2bf(acc[i][j][1] + bvv);
                o.z = f2bf(acc[i][j][2] + bvv);
                o.w = f2bf(acc[i][j][3] + bvv);
                long boff = (long)(mbase >> 11) * (1024L * 2048) + (long)n * 2048 + (mbase & 2047);
                *reinterpret_cast<ushort4*>(Vt + boff) = o;
            }
        }
    }
}

// =================== 8-phase pipelined NT-GEMM (scores, y) ==================
// LDS per buffer b, k-half h: A panel [rows][32] and B panel [rows][32],
// each k-half contiguous; physical 128B rows hold 2 logical rows; 16B slot
// s of physical row R holds logical row 2R+(s>>2), global k-chunk
// (s&3)^(R&3)  (XOR swizzle -> conflict-free ds_read_b128).
// Fragment loads are VOLATILE INLINE-ASM ds_read_b128 (invisible to the
// compiler's LDS-DMA waitcnt tracking); ordering enforced by s_barrier +
// counted vmcnt + lgkmcnt(0) + sched_barrier(0).

#define VMW(N) asm volatile("s_waitcnt vmcnt(" #N ")" ::: "memory")

#define DSR(dst, addr, IMM)                                                 \
    asm volatile("ds_read_b128 %0, %1 offset:%2"                            \
                 : "=v"(dst) : "v"(addr), "n"(IMM))

#define PIPE_DECLS                                                          \
    const int tid  = threadIdx.x;                                           \
    const int wave = tid >> 6;                                              \
    const int lane = tid & 63;                                              \
    const int quad = lane >> 4;                                             \
    const int lr   = lane & 15;                                             \
    const int wvm  = wave >> 2;      /* wave_m: 0..1 */                     \
    const int wvn  = wave & 3;       /* wave_n: 0..3 */                     \
    const int rd_off = (lr >> 1) * 64 + (lr & 1) * 32                       \
                     + ((quad ^ ((lr >> 1) & 3)) << 3);                     \
    const unsigned rdb = 2u * (unsigned)rd_off;                             \
    const unsigned ldsb = (unsigned)(unsigned long long)                    \
        (__attribute__((address_space(3))) void*)&lds[0];                   \
    const int stg_rl = wave * 16 + ((lane >> 3) << 1) + ((lane >> 2) & 1);  \
    const int stg_c  = (((lane & 3) ^ ((lane >> 3) & 3)) << 3);

// One global_load_lds instruction per wave: 64 lanes x 16B, linear LDS dest.
#define ST1(base, LD, kcol, dst, c)                                         \
    __builtin_amdgcn_global_load_lds(                                       \
        (const __attribute__((address_space(1))) void*)                     \
            ((base) + (long)(c) * 128 * (LD) + (kcol)),                     \
        (__attribute__((address_space(3))) void*)(&lds[(dst) + (c) * 4096 + wave * 512]), \
        16, 0, 0)

#define MF4(ci, A)                                                          \
    acc[ci][0] = __builtin_amdgcn_mfma_f32_16x16x32_bf16(A, bfr[0], acc[ci][0], 0, 0, 0); \
    acc[ci][1] = __builtin_amdgcn_mfma_f32_16x16x32_bf16(A, bfr[1], acc[ci][1], 0, 0, 0); \
    acc[ci][2] = __builtin_amdgcn_mfma_f32_16x16x32_bf16(A, bfr[2], acc[ci][2], 0, 0, 0); \
    acc[ci][3] = __builtin_amdgcn_mfma_f32_16x16x32_bf16(A, bfr[3], acc[ci][3], 0, 0, 0);

// ---- scores phase: IH=4 (A byte stride per frag 1024; h-stride 16384) ----
#define PHASE_S(AA, BB, h, mh, STG, WAITS)                                  \
    {                                                                       \
        if ((mh) == 0) {                                                    \
            DSR(bfr[0], BB, (h) * 16384 + 0);                               \
            DSR(bfr[1], BB, (h) * 16384 + 1024);                            \
            DSR(bfr[2], BB, (h) * 16384 + 2048);                            \
            DSR(bfr[3], BB, (h) * 16384 + 3072);                            \
        }                                                                   \
        bf16x8 af0, af1, af2, af3;                                          \
        DSR(af0, AA, (h) * 16384 + ((mh) * 4 + 0) * 1024);                  \
        DSR(af1, AA, (h) * 16384 + ((mh) * 4 + 1) * 1024);                  \
        DSR(af2, AA, (h) * 16384 + ((mh) * 4 + 2) * 1024);                  \
        DSR(af3, AA, (h) * 16384 + ((mh) * 4 + 3) * 1024);                  \
        STG;                                                                \
        WAITS;                                                              \
        __builtin_amdgcn_s_barrier();                                       \
        asm volatile("s_waitcnt lgkmcnt(0)");                               \
        __builtin_amdgcn_sched_barrier(0);                                  \
        __builtin_amdgcn_s_setprio(1);                                      \
        MF4((mh) * 4 + 0, af0); MF4((mh) * 4 + 1, af1);                     \
        MF4((mh) * 4 + 2, af2); MF4((mh) * 4 + 3, af3);                     \
        __builtin_amdgcn_sched_barrier(0);                                  \
        __builtin_amdgcn_s_setprio(0);                                      \
        __builtin_amdgcn_s_barrier();                                       \
    }

// ---- y phase: IH=2 (A h-stride 8192) ----
#define PHASE_Y(AA, BB, h, mh, STG, WAITS)                                  \
    {                                                                       \
        if ((mh) == 0) {                                                    \
            DSR(bfr[0], BB, (h) * 16384 + 0);                               \
            DSR(bfr[1], BB, (h) * 16384 + 1024);                            \
            DSR(bfr[2], BB, (h) * 16384 + 2048);                            \
            DSR(bfr[3], BB, (h) * 16384 + 3072);                            \
        }                                                                   \
        bf16x8 af0, af1;                                                    \
        DSR(af0, AA, (h) * 8192 + ((mh) * 2 + 0) * 1024);                   \
        DSR(af1, AA, (h) * 8192 + ((mh) * 2 + 1) * 1024);                   \
        STG;                                                                \
        WAITS;                                                              \
        __builtin_amdgcn_s_barrier();                                       \
        asm volatile("s_waitcnt lgkmcnt(0)");                               \
        __builtin_amdgcn_sched_barrier(0);                                  \
        __builtin_amdgcn_s_setprio(1);                                      \
        MF4((mh) * 2 + 0, af0); MF4((mh) * 2 + 1, af1);                     \
        __builtin_amdgcn_sched_barrier(0);                                  \
        __builtin_amdgcn_s_setprio(0);                                      \
        __builtin_amdgcn_s_barrier();                                       \
    }

// Stage schedule (tiles t=2it in buf0, t+1 in buf1; panel staged at phase p
// is consumed 6 phases later; its previous readers finished at phase p-1):
//   p0: A(t+1).k1->1   p1: B(t+1).k1->1   p2: A(t+2).k0->0  p3: B(t+2).k0->0 +vm
//   p4: A(t+2).k1->0   p5: B(t+2).k1->0   p6: A(t+3).k0->1  p7: B(t+3).k0->1 +vm
#define RUN8(PH, NT_, WAITST)                                               \
    SA(0, 0, 0); SB(0, 0, 0); SA(0, 1, 0); SB(0, 1, 0); SA(1, 0, 1); SB(1, 0, 1); \
    WAITST;                                                                 \
    __builtin_amdgcn_s_barrier();                                           \
    _Pragma("unroll 1")                                                     \
    for (int it = 0; it < (NT_) / 2 - 1; ++it) {                            \
        const int tb = 2 * it;                                              \
        PH(adr_a0, adr_b0, 0, 0, SA(tb + 1, 1, 1), )                        \
        PH(adr_a0, adr_b0, 0, 1, SB(tb + 1, 1, 1), )                        \
        PH(adr_a0, adr_b0, 1, 0, SA(tb + 2, 0, 0), )                        \
        PH(adr_a0, adr_b0, 1, 1, SB(tb + 2, 0, 0), WAITST)                  \
        PH(adr_a1, adr_b1, 0, 0, SA(tb + 2, 1, 0), )                        \
        PH(adr_a1, adr_b1, 0, 1, SB(tb + 2, 1, 0), )                        \
        PH(adr_a1, adr_b1, 1, 0, SA(tb + 3, 0, 1), )                        \
        PH(adr_a1, adr_b1, 1, 1, SB(tb + 3, 0, 1), WAITST)                  \
    }                                                                       \
    PH(adr_a0, adr_b0, 0, 0, SA((NT_) - 1, 1, 1), )                         \
    PH(adr_a0, adr_b0, 0, 1, SB((NT_) - 1, 1, 1), )                         \
    PH(adr_a0, adr_b0, 1, 0, , )                                            \
    PH(adr_a0, adr_b0, 1, 1, , WAITST)                                      \
    PH(adr_a1, adr_b1, 0, 0, , )                                            \
    PH(adr_a1, adr_b1, 0, 1, , VMW(0))                                      \
    PH(adr_a1, adr_b1, 1, 0, , )                                            \
    PH(adr_a1, adr_b1, 1, 1, , )

// ---------------- gemm_scores: 256x256 tile ----------------
#define SA(tt, h, b) { ST1(aBase, 1024, (tt) * 64 + (h) * 32, (b) * 32768 + (h) * 8192, 0); \
                       ST1(aBase, 1024, (tt) * 64 + (h) * 32, (b) * 32768 + (h) * 8192, 1); }
#define SB(tt, h, b) { ST1(bBase, 1024, (tt) * 64 + (h) * 32, (b) * 32768 + 16384 + (h) * 8192, 0); \
                       ST1(bBase, 1024, (tt) * 64 + (h) * 32, (b) * 32768 + 16384 + (h) * 8192, 1); }

// Scores + fused exp: P[b][j][i] = exp(Q_j.K_i*scale) (bf16), l += row sums.
// 256 blocks = exactly 1/CU: g=id&7 -> batch g>>1, m-half g&1; u=id>>3:
// mt=(g&1)*4+(u&3), nt=u>>2.
__global__ __launch_bounds__(512, 2)
void gemm_scores(const unsigned short* __restrict__ Q,
                 const unsigned short* __restrict__ Kp,
                 unsigned short* __restrict__ P, float* __restrict__ l,
                 float scale)
{
    __shared__ __align__(16) unsigned short lds[65536];   // 128 KB

    const int id = blockIdx.x;
    const int g  = id & 7;
    const int u  = id >> 3;
    const int bz = g >> 1;
    const int m0 = ((g & 1) * 4 + (u & 3)) * 256;
    const int n0 = (u >> 2) * 256;

    const unsigned short* Aptr = Q  + (long)bz * 2048 * 1024;
    const unsigned short* Bptr = Kp + (long)bz * 2048 * 1024;
    unsigned short* Pb = P + (long)bz * 2048 * 2048;
    float* lb = l + bz * 2048;

    PIPE_DECLS
    const unsigned short* aBase = Aptr + (long)(m0 + stg_rl) * 1024 + stg_c;
    const unsigned short* bBase = Bptr + (long)(n0 + stg_rl) * 1024 + stg_c;

    // asm ds_read address registers (bytes): A frag row stride 1024B,
    // buffer stride 65536B; B panel at +32768B, wvn group stride 4096B.
    const unsigned adr_a0 = ldsb + (unsigned)(wvm * 8192) + rdb;
    const unsigned adr_a1 = adr_a0 + 65536u;
    const unsigned adr_b0 = ldsb + 32768u + (unsigned)(wvn * 4096) + rdb;
    const unsigned adr_b1 = adr_b0 + 65536u;

    f32x4 acc[8][4] = {};
    bf16x8 bfr[4];
    RUN8(PHASE_S, 16, VMW(4))

#pragma unroll
    for (int i = 0; i < 8; ++i) {
#pragma unroll
        for (int r = 0; r < 4; ++r) {
            const int m = m0 + wvm * 128 + i * 16 + quad * 4 + r;
            float psum = 0.0f;
#pragma unroll
            for (int j = 0; j < 4; ++j) {
                const float p = __expf(acc[i][j][r] * scale);
                psum += p;
                Pb[(long)m * 2048 + (n0 + wvn * 64 + j * 16 + lr)] = f2bf(p);
            }
#pragma unroll
            for (int o = 1; o < 16; o <<= 1) psum += __shfl_xor(psum, o, 64);
            if (lr == 0) atomicAdd(&lb[m], psum);
        }
    }
}

#undef SA
#undef SB

// ---------------- gemm_y: 128x256 tile ----------------
#define SA(tt, h, b) { ST1(aBase, 2048, (tt) * 64 + (h) * 32, (b) * 24576 + (h) * 4096, 0); }
#define SB(tt, h, b) { ST1(bBase, 2048, (tt) * 64 + (h) * 32, (b) * 24576 + 8192 + (h) * 8192, 0); \
                       ST1(bBase, 2048, (tt) * 64 + (h) * 32, (b) * 24576 + 8192 + (h) * 8192, 1); }

// Y[b][j][d] = (1/l[b,j]) * sum_i P[b][j][i]*Vt[b][d][i] -> fp32 out.
// 256 blocks (full wave): g=id&7 -> batch g>>1, m-half g&1; u=id>>3:
// mt=(g&1)*8+(u&7), nt=u>>3. K=2048 -> NT=32, per-stage A=1/B=2 loads -> vmcnt(3).
__global__ __launch_bounds__(512, 2)
void gemm_y(const unsigned short* __restrict__ P,
            const unsigned short* __restrict__ Vt,
            const float* __restrict__ l, float* __restrict__ out)
{
    __shared__ __align__(16) unsigned short lds[49152];   // 96 KB

    const int id = blockIdx.x;
    const int g  = id & 7;
    const int u  = id >> 3;
    const int bz = g >> 1;
    const int m0 = ((g & 1) * 8 + (u & 7)) * 128;
    const int n0 = (u >> 3) * 256;

    const unsigned short* Aptr = P  + (long)bz * 2048 * 2048;
    const unsigned short* Bptr = Vt + (long)bz * 1024 * 2048;
    const float* lb = l + bz * 2048;
    float* C = out + (long)bz * 2048 * 1024;

    PIPE_DECLS
    const unsigned short* aBase = Aptr + (long)(m0 + stg_rl) * 2048 + stg_c;
    const unsigned short* bBase = Bptr + (long)(n0 + stg_rl) * 2048 + stg_c;

    // A: buffer stride 49152B, h-stride 8192B, wvm group stride 4096B.
    // B: panel at +16384B within buffer, h-stride 16384B, wvn stride 4096B.
    const unsigned adr_a0 = ldsb + (unsigned)(wvm * 4096) + rdb;
    const unsigned adr_a1 = adr_a0 + 49152u;
    const unsigned adr_b0 = ldsb + 16384u + (unsigned)(wvn * 4096) + rdb;
    const unsigned adr_b1 = adr_b0 + 49152u;

    f32x4 acc[4][4] = {};
    bf16x8 bfr[4];
    RUN8(PHASE_Y, 32, VMW(3))

    float linv[4][4];
#pragma unroll
    for (int i = 0; i < 4; ++i)
#pragma unroll
        for (int r = 0; r < 4; ++r)
            linv[i][r] = 1.0f / lb[m0 + wvm * 64 + i * 16 + quad * 4 + r];

#pragma unroll
    for (int j = 0; j < 4; ++j) {
        const int n = n0 + wvn * 64 + j * 16 + lr;
#pragma unroll
        for (int i = 0; i < 4; ++i) {
            const int mbase = m0 + wvm * 64 + i * 16 + quad * 4;
#pragma unroll
            for (int r = 0; r < 4; ++r)
                C[(long)(mbase + r) * 1024 + n] = acc[i][j][r] * linv[i][r];
        }
    }
}

#undef SA
#undef SB

extern "C" void kernel_launch(void* const* d_in, const int* in_sizes, int n_in,
                              void* d_out, int out_size, void* d_ws, size_t ws_size,
                              hipStream_t stream) {
    const float* X  = (const float*)d_in[0];
    const float* Wk = (const float*)d_in[1];
    const float* bk = (const float*)d_in[2];
    const float* Wq = (const float*)d_in[3];
    const float* bq = (const float*)d_in[4];
    const float* Wv = (const float*)d_in[5];
    const float* bv = (const float*)d_in[6];
    float* out = (float*)d_out;

    const size_t MB = 1024 * 1024;
    if (ws_size < 80 * MB) return;   // visible failure instead of OOB corruption

    char* ws = (char*)d_ws;
    unsigned short* Vt  = (unsigned short*)(ws);            // 16 MiB, live to the end
    unsigned short* P   = (unsigned short*)(ws + 16 * MB);  // 32 MiB bf16 scores/probs
    unsigned short* Xbf = (unsigned short*)(ws + 16 * MB);  // overlaps P: dead before P written
    float*          l   = (float*)(ws + 48 * MB);           // 32 KiB row sums
    unsigned short* Wqb = (unsigned short*)(ws + 49 * MB);
    unsigned short* Wkb = (unsigned short*)(ws + 51 * MB);
    unsigned short* Wvb = (unsigned short*)(ws + 53 * MB);
    // Q,K bf16 live in d_out (32 MiB) until gemm_y overwrites it
    unsigned short* Qb = (unsigned short*)d_out;
    unsigned short* Kb = Qb + 8192L * 1024;

    // 1) fp32->bf16 conversions + zero l (2883584 float4 units)
    cvt_all<<<2883584 / 256, dim3(256), 0, stream>>>(X, Wq, Wk, Wv, Xbf, Wqb, Wkb, Wvb, l);

    // 2) fused QKV projections: R6 m97-style, 1536 blocks x 256 threads
    gemm_qkv<<<1536, dim3(256), 0, stream>>>(Xbf, Wqb, Wkb, Wvb, bq, bk, bv, Qb, Kb, Vt);

    // 3) scores + exp + row-sum atomics: 256 blocks (1/CU), 8-phase + asm reads
    gemm_scores<<<256, dim3(512), 0, stream>>>(Qb, Kb, P, l, 0.022097086912079608f);

    // 4) Y = (P @ Vt^T) / l: 256 blocks, 8-phase + asm reads
    gemm_y<<<256, dim3(512), 0, stream>>>(P, Vt, l, out);
}

// Round 4
// 225.366 us; speedup vs baseline: 1.0105x; 1.0105x over previous
//
#include <hip/hip_runtime.h>
#include <hip/hip_bf16.h>

// SelfAttention: B=4, S=2048, E=1024, fp32 in/out, bf16 internal compute.
// Y[b,j,d] = sum_i softmax_i(Q_j.K_i / sqrt(S)) * V[i,d]
//
// R10: measured-best recombination.
//  - gemm_qkv: m97-style 128^2 tile, 1536 blocks (measured 63-67us, ~805 TF
//    via 6 blocks/CU wave-level overlap).
//  - gemm_scores / gemm_y: 8-phase counted-vmcnt pipeline in its R7 form —
//    NO lgkmcnt(0) pin, NO sched_barrier(0). Cross-round decomposition showed
//    the R8 pins cost ~29us: s_barrier is not a compiler fence, so the
//    compiler software-pipelines next-phase ds_reads into the MFMA cluster
//    with partial lgkm waits; sched_barrier(0) destroyed that overlap.
//    (R7 measured scores+y ~118us combined vs ~146us pinned.)

typedef __bf16 bf16x8 __attribute__((ext_vector_type(8)));
typedef float  f32x4  __attribute__((ext_vector_type(4)));

__device__ __forceinline__ unsigned short f2bf(float f) {
    unsigned int u = __float_as_uint(f);
    u = (u + 0x7FFFu + ((u >> 16) & 1u)) >> 16;   // round-to-nearest-even
    return (unsigned short)u;
}

// Converts X + Wq/Wk/Wv fp32->bf16, and zeroes the softmax-denominator array.
__global__ __launch_bounds__(256)
void cvt_all(const float* __restrict__ X,  const float* __restrict__ Wq,
             const float* __restrict__ Wk, const float* __restrict__ Wv,
             unsigned short* __restrict__ Xb,  unsigned short* __restrict__ Wqb,
             unsigned short* __restrict__ Wkb, unsigned short* __restrict__ Wvb,
             float* __restrict__ l) {
    long i = (long)blockIdx.x * 256 + threadIdx.x;   // float4 index
    if (i < 8192) l[i] = 0.0f;                       // 4*2048 row sums
    const float* src; unsigned short* dst; long off;
    if (i < 2097152L) { src = X; dst = Xb; off = i; }
    else {
        long j = i - 2097152L;
        int w = (int)(j >> 18);          // 262144 float4 per 1024^2 matrix
        off = j & 262143L;
        src = (w == 0) ? Wq : (w == 1) ? Wk : Wv;
        dst = (w == 0) ? Wqb : (w == 1) ? Wkb : Wvb;
    }
    float4 v = reinterpret_cast<const float4*>(src)[off];
    ushort4 o;
    o.x = f2bf(v.x); o.y = f2bf(v.y); o.z = f2bf(v.z); o.w = f2bf(v.w);
    reinterpret_cast<ushort4*>(dst)[off] = o;
}

// ======================= R6 m97-style machinery (qkv) =======================
#define GEMM_DECLS                                                      \
    const int t    = threadIdx.x;                                       \
    const int wave = t >> 6;                                            \
    const int lane = t & 63;                                            \
    const int quad = lane >> 4;                                         \
    const int lr   = lane & 15;                                         \
    const int wm   = (wave >> 1) * 64;                                  \
    const int wn   = (wave & 1) * 64;                                   \
    const int sx   = lr & 7;                                            \
    const int lrow = lane >> 3;                                         \
    const int gch  = ((lane & 7) ^ (lrow & 7)) * 8;

#define GEMM_KLOOP(Aptr, Bptr, LDA, LDB)                                \
    for (int k0 = 0; k0 < K; k0 += 64) {                                \
        _Pragma("unroll")                                               \
        for (int r = 0; r < 4; ++r) {                                   \
            const int rowb = wave * 8 + r * 32;                         \
            const int row  = rowb + lrow;                               \
            const long goffA = (long)(m0 + row) * (LDA) + k0 + gch;     \
            const long goffB = (long)(n0 + row) * (LDB) + k0 + gch;     \
            __builtin_amdgcn_global_load_lds(                           \
                (const __attribute__((address_space(1))) void*)((Aptr) + goffA), \
                (__attribute__((address_space(3))) void*)(&lsA[rowb * 64]), 16, 0, 0); \
            __builtin_amdgcn_global_load_lds(                           \
                (const __attribute__((address_space(1))) void*)((Bptr) + goffB), \
                (__attribute__((address_space(3))) void*)(&lsB[rowb * 64]), 16, 0, 0); \
        }                                                               \
        __syncthreads();                                                \
        _Pragma("unroll")                                               \
        for (int h = 0; h < 2; ++h) {                                   \
            const int cp = ((h * 4 + quad) ^ sx) * 8;                   \
            bf16x8 af[4], bfr[4];                                       \
            _Pragma("unroll")                                           \
            for (int i = 0; i < 4; ++i) {                               \
                af[i]  = __builtin_bit_cast(bf16x8,                     \
                          *reinterpret_cast<const uint4*>(&lsA[(wm + i * 16 + lr) * 64 + cp])); \
                bfr[i] = __builtin_bit_cast(bf16x8,                     \
                          *reinterpret_cast<const uint4*>(&lsB[(wn + i * 16 + lr) * 64 + cp])); \
            }                                                           \
            _Pragma("unroll")                                           \
            for (int i = 0; i < 4; ++i)                                 \
                _Pragma("unroll")                                       \
                for (int j = 0; j < 4; ++j)                             \
                    acc[i][j] = __builtin_amdgcn_mfma_f32_16x16x32_bf16(af[i], bfr[j], acc[i][j], 0, 0, 0); \
        }                                                               \
        __syncthreads();                                                \
    }

// Fused QKV projection, XCD-band swizzled 1D grid of 1536 blocks:
// id = g + 8*(x + 8*y_in + 64*z); XCD g owns m-band y = g*8+y_in.
// z=0 -> Q (bf16), z=1 -> K (bf16), z=2 -> V transposed Vt[b][n][s].
__global__ __launch_bounds__(256, 2)
void gemm_qkv(const unsigned short* __restrict__ Xb,
              const unsigned short* __restrict__ Wqb,
              const unsigned short* __restrict__ Wkb,
              const unsigned short* __restrict__ Wvb,
              const float* __restrict__ bq, const float* __restrict__ bk,
              const float* __restrict__ bv_,
              unsigned short* __restrict__ Qb, unsigned short* __restrict__ Kb,
              unsigned short* __restrict__ Vt)
{
    __shared__ unsigned short lsA[128 * 64];
    __shared__ unsigned short lsB[128 * 64];

    const int id  = blockIdx.x;
    const int g   = id & 7;
    const int jj  = id >> 3;
    const int xx  = jj & 7;
    const int yin = (jj >> 3) & 7;
    const int z   = jj >> 6;

    const unsigned short* A = Xb;
    const unsigned short* B = (z == 0) ? Wqb : (z == 1) ? Wkb : Wvb;
    const float* bias       = (z == 0) ? bq  : (z == 1) ? bk  : bv_;

    const int n0 = xx * 128;
    const int m0 = (g * 8 + yin) * 128;
    const int K = 1024;

    GEMM_DECLS
    f32x4 acc[4][4] = {};
    GEMM_KLOOP(A, B, 1024, 1024)

#pragma unroll
    for (int j = 0; j < 4; ++j) {
        const int n = n0 + wn + j * 16 + lr;
        const float bvv = bias[n];
#pragma unroll
        for (int i = 0; i < 4; ++i) {
            const int mbase = m0 + wm + i * 16 + quad * 4;
            if (z < 2) {
                unsigned short* C = (z == 0) ? Qb : Kb;
#pragma unroll
                for (int r = 0; r < 4; ++r)
                    C[(long)(mbase + r) * 1024 + n] = f2bf(acc[i][j][r] + bvv);
            } else {
                ushort4 o;
                o.x = f2bf(acc[i][j][0] + bvv);
                o.y = f2bf(acc[i][j][1] + bvv);
                o.z = f2bf(acc[i][j][2] + bvv);
                o.w = f2bf(acc[i][j][3] + bvv);
                long boff = (long)(mbase >> 11) * (1024L * 2048) + (long)n * 2048 + (mbase & 2047);
                *reinterpret_cast<ushort4*>(Vt + boff) = o;
            }
        }
    }
}

// =================== 8-phase pipelined NT-GEMM (scores, y) ==================
// LDS per buffer b, k-half h: A panel [rows][32] and B panel [rows][32],
// each k-half contiguous; physical 128B rows hold 2 logical rows; 16B slot
// s of physical row R holds logical row 2R+(s>>2), global k-chunk
// (s&3)^(R&3)  (XOR swizzle -> conflict-free ds_read_b128).

#define VMW(N) asm volatile("s_waitcnt vmcnt(" #N ")" ::: "memory")

#define PIPE_DECLS                                                          \
    const int tid  = threadIdx.x;                                           \
    const int wave = tid >> 6;                                              \
    const int lane = tid & 63;                                              \
    const int quad = lane >> 4;                                             \
    const int lr   = lane & 15;                                             \
    const int wvm  = wave >> 2;      /* wave_m: 0..1 */                     \
    const int wvn  = wave & 3;       /* wave_n: 0..3 */                     \
    const int rd_off = (lr >> 1) * 64 + (lr & 1) * 32                       \
                     + ((quad ^ ((lr >> 1) & 3)) << 3);                     \
    const int stg_rl = wave * 16 + ((lane >> 3) << 1) + ((lane >> 2) & 1);  \
    const int stg_c  = (((lane & 3) ^ ((lane >> 3) & 3)) << 3);

// One global_load_lds instruction per wave: 64 lanes x 16B, linear LDS dest.
#define ST1(base, LD, kcol, dst, c)                                         \
    __builtin_amdgcn_global_load_lds(                                       \
        (const __attribute__((address_space(1))) void*)                     \
            ((base) + (long)(c) * 128 * (LD) + (kcol)),                     \
        (__attribute__((address_space(3))) void*)(&lds[(dst) + (c) * 4096 + wave * 512]), \
        16, 0, 0)

// Phase: read fragments of (buffer bs, k-half h, m-half mh); stage STG;
// wait WAITS; barrier; MFMA cluster; barrier. NO compiler pins (R7 form):
// the compiler software-pipelines next-phase ds_reads into the MFMA cluster
// with partial lgkm waits on its own.
#define PHASE(bs, h, mh, IH_, STG, WAITS)                                   \
    {                                                                       \
        if ((mh) == 0) {                                                    \
            _Pragma("unroll")                                               \
            for (int j = 0; j < 4; ++j)                                     \
                bfr[j] = __builtin_bit_cast(bf16x8,                         \
                    *reinterpret_cast<const uint4*>(                        \
                        &lds[BOFF(bs, h) + (wvn * 4 + j) * 512 + rd_off])); \
        }                                                                   \
        bf16x8 af[IH_];                                                     \
        _Pragma("unroll")                                                   \
        for (int i = 0; i < (IH_); ++i)                                     \
            af[i] = __builtin_bit_cast(bf16x8,                              \
                *reinterpret_cast<const uint4*>(                            \
                    &lds[AOFF(bs, h) + (wvm * 2 * (IH_) + (mh) * (IH_) + i) * 512 + rd_off])); \
        STG;                                                                \
        WAITS;                                                              \
        __builtin_amdgcn_s_barrier();                                       \
        __builtin_amdgcn_s_setprio(1);                                      \
        _Pragma("unroll")                                                   \
        for (int i = 0; i < (IH_); ++i)                                     \
            _Pragma("unroll")                                               \
            for (int j = 0; j < 4; ++j)                                     \
                acc[(mh) * (IH_) + i][j] = __builtin_amdgcn_mfma_f32_16x16x32_bf16( \
                    af[i], bfr[j], acc[(mh) * (IH_) + i][j], 0, 0, 0);      \
        __builtin_amdgcn_s_setprio(0);                                      \
        __builtin_amdgcn_s_barrier();                                       \
    }

// Stage schedule (tiles t=2it in buf0, t+1 in buf1; panel staged at phase p
// is consumed 6 phases later; its previous readers finished at phase p-1):
//   p0: A(t+1).k1->1   p1: B(t+1).k1->1   p2: A(t+2).k0->0  p3: B(t+2).k0->0 +vm
//   p4: A(t+2).k1->0   p5: B(t+2).k1->0   p6: A(t+3).k0->1  p7: B(t+3).k0->1 +vm
#define RUN_PIPELINE(IH_, NT_, WAITST)                                      \
    f32x4 acc[2 * (IH_)][4] = {};                                           \
    bf16x8 bfr[4];                                                          \
    SA(0, 0, 0); SB(0, 0, 0); SA(0, 1, 0); SB(0, 1, 0); SA(1, 0, 1); SB(1, 0, 1); \
    WAITST;                                                                 \
    __builtin_amdgcn_s_barrier();                                           \
    _Pragma("unroll 1")                                                     \
    for (int it = 0; it < (NT_) / 2 - 1; ++it) {                            \
        const int tb = 2 * it;                                              \
        PHASE(0, 0, 0, IH_, SA(tb + 1, 1, 1), )                             \
        PHASE(0, 0, 1, IH_, SB(tb + 1, 1, 1), )                             \
        PHASE(0, 1, 0, IH_, SA(tb + 2, 0, 0), )                             \
        PHASE(0, 1, 1, IH_, SB(tb + 2, 0, 0), WAITST)                       \
        PHASE(1, 0, 0, IH_, SA(tb + 2, 1, 0), )                             \
        PHASE(1, 0, 1, IH_, SB(tb + 2, 1, 0), )                             \
        PHASE(1, 1, 0, IH_, SA(tb + 3, 0, 1), )                             \
        PHASE(1, 1, 1, IH_, SB(tb + 3, 0, 1), WAITST)                       \
    }                                                                       \
    PHASE(0, 0, 0, IH_, SA((NT_) - 1, 1, 1), )                              \
    PHASE(0, 0, 1, IH_, SB((NT_) - 1, 1, 1), )                              \
    PHASE(0, 1, 0, IH_, , )                                                 \
    PHASE(0, 1, 1, IH_, , WAITST)                                           \
    PHASE(1, 0, 0, IH_, , )                                                 \
    PHASE(1, 0, 1, IH_, , VMW(0))                                           \
    PHASE(1, 1, 0, IH_, , )                                                 \
    PHASE(1, 1, 1, IH_, , )

// ---------------- gemm_scores: 256x256 tile ----------------
#define AOFF(b, h) ((b) * 32768 + (h) * 8192)
#define BOFF(b, h) ((b) * 32768 + 16384 + (h) * 8192)
#define SA(tt, h, b) { ST1(aBase, 1024, (tt) * 64 + (h) * 32, AOFF(b, h), 0); \
                       ST1(aBase, 1024, (tt) * 64 + (h) * 32, AOFF(b, h), 1); }
#define SB(tt, h, b) { ST1(bBase, 1024, (tt) * 64 + (h) * 32, BOFF(b, h), 0); \
                       ST1(bBase, 1024, (tt) * 64 + (h) * 32, BOFF(b, h), 1); }

// Scores + fused exp: P[b][j][i] = exp(Q_j.K_i*scale) (bf16), l += row sums.
// 256 blocks = exactly 1/CU: g=id&7 -> batch g>>1, m-half g&1; u=id>>3:
// mt=(g&1)*4+(u&3), nt=u>>2.
__global__ __launch_bounds__(512, 2)
void gemm_scores(const unsigned short* __restrict__ Q,
                 const unsigned short* __restrict__ Kp,
                 unsigned short* __restrict__ P, float* __restrict__ l,
                 float scale)
{
    __shared__ __align__(16) unsigned short lds[65536];   // 128 KB

    const int id = blockIdx.x;
    const int g  = id & 7;
    const int u  = id >> 3;
    const int bz = g >> 1;
    const int m0 = ((g & 1) * 4 + (u & 3)) * 256;
    const int n0 = (u >> 2) * 256;

    const unsigned short* Aptr = Q  + (long)bz * 2048 * 1024;
    const unsigned short* Bptr = Kp + (long)bz * 2048 * 1024;
    unsigned short* Pb = P + (long)bz * 2048 * 2048;
    float* lb = l + bz * 2048;

    PIPE_DECLS
    const unsigned short* aBase = Aptr + (long)(m0 + stg_rl) * 1024 + stg_c;
    const unsigned short* bBase = Bptr + (long)(n0 + stg_rl) * 1024 + stg_c;

    RUN_PIPELINE(4, 16, VMW(4))

#pragma unroll
    for (int i = 0; i < 8; ++i) {
#pragma unroll
        for (int r = 0; r < 4; ++r) {
            const int m = m0 + wvm * 128 + i * 16 + quad * 4 + r;
            float psum = 0.0f;
#pragma unroll
            for (int j = 0; j < 4; ++j) {
                const float p = __expf(acc[i][j][r] * scale);
                psum += p;
                Pb[(long)m * 2048 + (n0 + wvn * 64 + j * 16 + lr)] = f2bf(p);
            }
#pragma unroll
            for (int o = 1; o < 16; o <<= 1) psum += __shfl_xor(psum, o, 64);
            if (lr == 0) atomicAdd(&lb[m], psum);
        }
    }
}

#undef SA
#undef SB
#undef AOFF
#undef BOFF

// ---------------- gemm_y: 128x256 tile, A rows 128 (1 call) -------------
#define AOFF(b, h) ((b) * 24576 + (h) * 4096)
#define BOFF(b, h) ((b) * 24576 + 8192 + (h) * 8192)
#define SA(tt, h, b) { ST1(aBase, 2048, (tt) * 64 + (h) * 32, AOFF(b, h), 0); }
#define SB(tt, h, b) { ST1(bBase, 2048, (tt) * 64 + (h) * 32, BOFF(b, h), 0); \
                       ST1(bBase, 2048, (tt) * 64 + (h) * 32, BOFF(b, h), 1); }

// Y[b][j][d] = (1/l[b,j]) * sum_i P[b][j][i]*Vt[b][d][i] -> fp32 out.
// 256 blocks (full wave): g=id&7 -> batch g>>1, m-half g&1; u=id>>3:
// mt=(g&1)*8+(u&7), nt=u>>3. K=2048 -> NT=32, per-stage A=1/B=2 loads -> vmcnt(3).
__global__ __launch_bounds__(512, 2)
void gemm_y(const unsigned short* __restrict__ P,
            const unsigned short* __restrict__ Vt,
            const float* __restrict__ l, float* __restrict__ out)
{
    __shared__ __align__(16) unsigned short lds[49152];   // 96 KB

    const int id = blockIdx.x;
    const int g  = id & 7;
    const int u  = id >> 3;
    const int bz = g >> 1;
    const int m0 = ((g & 1) * 8 + (u & 7)) * 128;
    const int n0 = (u >> 3) * 256;

    const unsigned short* Aptr = P  + (long)bz * 2048 * 2048;
    const unsigned short* Bptr = Vt + (long)bz * 1024 * 2048;
    const float* lb = l + bz * 2048;
    float* C = out + (long)bz * 2048 * 1024;

    PIPE_DECLS
    const unsigned short* aBase = Aptr + (long)(m0 + stg_rl) * 2048 + stg_c;
    const unsigned short* bBase = Bptr + (long)(n0 + stg_rl) * 2048 + stg_c;

    RUN_PIPELINE(2, 32, VMW(3))

    float linv[4][4];
#pragma unroll
    for (int i = 0; i < 4; ++i)
#pragma unroll
        for (int r = 0; r < 4; ++r)
            linv[i][r] = 1.0f / lb[m0 + wvm * 64 + i * 16 + quad * 4 + r];

#pragma unroll
    for (int j = 0; j < 4; ++j) {
        const int n = n0 + wvn * 64 + j * 16 + lr;
#pragma unroll
        for (int i = 0; i < 4; ++i) {
            const int mbase = m0 + wvm * 64 + i * 16 + quad * 4;
#pragma unroll
            for (int r = 0; r < 4; ++r)
                C[(long)(mbase + r) * 1024 + n] = acc[i][j][r] * linv[i][r];
        }
    }
}

#undef SA
#undef SB
#undef AOFF
#undef BOFF

extern "C" void kernel_launch(void* const* d_in, const int* in_sizes, int n_in,
                              void* d_out, int out_size, void* d_ws, size_t ws_size,
                              hipStream_t stream) {
    const float* X  = (const float*)d_in[0];
    const float* Wk = (const float*)d_in[1];
    const float* bk = (const float*)d_in[2];
    const float* Wq = (const float*)d_in[3];
    const float* bq = (const float*)d_in[4];
    const float* Wv = (const float*)d_in[5];
    const float* bv = (const float*)d_in[6];
    float* out = (float*)d_out;

    const size_t MB = 1024 * 1024;
    if (ws_size < 80 * MB) return;   // visible failure instead of OOB corruption

    char* ws = (char*)d_ws;
    unsigned short* Vt  = (unsigned short*)(ws);            // 16 MiB, live to the end
    unsigned short* P   = (unsigned short*)(ws + 16 * MB);  // 32 MiB bf16 scores/probs
    unsigned short* Xbf = (unsigned short*)(ws + 16 * MB);  // overlaps P: dead before P written
    float*          l   = (float*)(ws + 48 * MB);           // 32 KiB row sums
    unsigned short* Wqb = (unsigned short*)(ws + 49 * MB);
    unsigned short* Wkb = (unsigned short*)(ws + 51 * MB);
    unsigned short* Wvb = (unsigned short*)(ws + 53 * MB);
    // Q,K bf16 live in d_out (32 MiB) until gemm_y overwrites it
    unsigned short* Qb = (unsigned short*)d_out;
    unsigned short* Kb = Qb + 8192L * 1024;

    // 1) fp32->bf16 conversions + zero l (2883584 float4 units)
    cvt_all<<<2883584 / 256, dim3(256), 0, stream>>>(X, Wq, Wk, Wv, Xbf, Wqb, Wkb, Wvb, l);

    // 2) fused QKV projections: R6 m97-style, 1536 blocks x 256 threads
    gemm_qkv<<<1536, dim3(256), 0, stream>>>(Xbf, Wqb, Wkb, Wvb, bq, bk, bv, Qb, Kb, Vt);

    // 3) scores + exp + row-sum atomics: 256 blocks (1/CU), 8-phase (R7 form)
    gemm_scores<<<256, dim3(512), 0, stream>>>(Qb, Kb, P, l, 0.022097086912079608f);

    // 4) Y = (P @ Vt^T) / l: 256 blocks, 8-phase (R7 form)
    gemm_y<<<256, dim3(512), 0, stream>>>(P, Vt, l, out);
}